// Round 1
// baseline (465.638 us; speedup 1.0000x reference)
//
#include <hip/hip_runtime.h>

#define HEAD_NUM 32
#define D_K 128
#define HIDDEN 4096
#define MAX_BS 16
#define MAX_SEQ 2048

// ---------------------------------------------------------------------------
// Kernel 1: q/k/v = x @ {w_q,w_k,w_v}.  (16x4096) @ (4096x4096) x3.
// Memory-bound on weights (192 MB). k-split over the reduction dim with
// fp32 atomics into a zeroed workspace. Weight reads coalesced (lane = col).
// ---------------------------------------------------------------------------
__global__ __launch_bounds__(256) void qkv_kernel(
    const float* __restrict__ x,
    const float* __restrict__ w_q,
    const float* __restrict__ w_k,
    const float* __restrict__ w_v,
    float* __restrict__ qkv)     // [3][MAX_BS][HIDDEN], pre-zeroed
{
    __shared__ float xs[MAX_BS][512];
    const int colTile = blockIdx.x;   // 0..15
    const int kChunk  = blockIdx.y;   // 0..7  (chunks of 512 along reduction)
    const int mat     = blockIdx.z;   // 0..2
    const int tid     = threadIdx.x;

    const float* W = (mat == 0) ? w_q : (mat == 1) ? w_k : w_v;
    float* outp = qkv + (size_t)mat * (MAX_BS * HIDDEN);

    // stage x[b][kChunk*512 .. +512) into LDS (float4, coalesced)
    for (int idx = tid; idx < MAX_BS * 512 / 4; idx += 256) {
        int b = idx >> 7;        // 128 float4 per row
        int f = idx & 127;
        *reinterpret_cast<float4*>(&xs[b][f * 4]) =
            *reinterpret_cast<const float4*>(&x[b * HIDDEN + kChunk * 512 + f * 4]);
    }
    __syncthreads();

    const int col = colTile * 256 + tid;
    float acc[MAX_BS];
    #pragma unroll
    for (int b = 0; b < MAX_BS; ++b) acc[b] = 0.f;

    const float* wcol = W + (size_t)(kChunk * 512) * HIDDEN + col;
    #pragma unroll 4
    for (int ii = 0; ii < 512; ++ii) {
        float w = wcol[(size_t)ii * HIDDEN];   // coalesced across lanes
        #pragma unroll
        for (int b = 0; b < MAX_BS; ++b)
            acc[b] = fmaf(xs[b][ii], w, acc[b]);  // LDS broadcast read
    }

    #pragma unroll
    for (int b = 0; b < MAX_BS; ++b)
        atomicAdd(&outp[b * HIDDEN + col], acc[b]);
}

// ---------------------------------------------------------------------------
// Kernel 2: attention for one (b,h) per block. 256 threads = 8 groups of 32.
// Each 32-lane group dots q against one K row per iteration (float4/lane,
// one fully-coalesced 512B row per group). Softmax in LDS. PV same pattern.
// Position start_pos uses the freshly-projected k,v from workspace
// (inputs must not be mutated).
// ---------------------------------------------------------------------------
__global__ __launch_bounds__(256) void attn_kernel(
    const float* __restrict__ cache_k,
    const float* __restrict__ cache_v,
    const float* __restrict__ qkv,
    const int*   __restrict__ start_pos_p,
    float* __restrict__ attn_out)   // [MAX_BS][HIDDEN]
{
    const int h   = blockIdx.x;
    const int b   = blockIdx.y;
    const int tid = threadIdx.x;
    const int start_pos = *start_pos_p;
    const int seq_len   = start_pos + 1;

    __shared__ float sc[MAX_SEQ];        // scores -> probs
    __shared__ float red[8];             // cross-wave reductions
    __shared__ float partial[8][D_K];    // PV partial sums per group

    const float* q    = qkv + 0 * (MAX_BS * HIDDEN) + b * HIDDEN + h * D_K;
    const float* knew = qkv + 1 * (MAX_BS * HIDDEN) + b * HIDDEN + h * D_K;
    const float* vnew = qkv + 2 * (MAX_BS * HIDDEN) + b * HIDDEN + h * D_K;

    const int lane32 = tid & 31;
    const int grp    = tid >> 5;         // 0..7
    const int wid    = tid >> 6;         // 0..3

    const float4 qf = *reinterpret_cast<const float4*>(&q[lane32 * 4]);
    const float scale = 0.08838834764831845f;   // 1/sqrt(128)

    // ---- phase 1: scores -------------------------------------------------
    for (int s = grp; s < seq_len; s += 8) {
        const float* krow = (s == start_pos)
            ? knew
            : cache_k + (((size_t)b * MAX_SEQ + s) * HEAD_NUM + h) * D_K;
        const float4 kf = *reinterpret_cast<const float4*>(&krow[lane32 * 4]);
        float p = qf.x * kf.x + qf.y * kf.y + qf.z * kf.z + qf.w * kf.w;
        p += __shfl_xor(p, 16);
        p += __shfl_xor(p, 8);
        p += __shfl_xor(p, 4);
        p += __shfl_xor(p, 2);
        p += __shfl_xor(p, 1);
        if (lane32 == 0) sc[s] = p * scale;
    }
    __syncthreads();

    // ---- phase 2: softmax ------------------------------------------------
    float m = -INFINITY;
    for (int s = tid; s < seq_len; s += 256) m = fmaxf(m, sc[s]);
    #pragma unroll
    for (int off = 32; off; off >>= 1) m = fmaxf(m, __shfl_xor(m, off));
    if ((tid & 63) == 0) red[wid] = m;
    __syncthreads();
    m = fmaxf(fmaxf(red[0], red[1]), fmaxf(red[2], red[3]));

    float sum = 0.f;
    for (int s = tid; s < seq_len; s += 256) {
        float e = __expf(sc[s] - m);
        sc[s] = e;
        sum += e;
    }
    #pragma unroll
    for (int off = 32; off; off >>= 1) sum += __shfl_xor(sum, off);
    if ((tid & 63) == 0) red[4 + wid] = sum;
    __syncthreads();
    const float inv_sum = 1.0f / (red[4] + red[5] + red[6] + red[7]);

    // ---- phase 3: PV -----------------------------------------------------
    float4 accv = {0.f, 0.f, 0.f, 0.f};
    for (int s = grp; s < seq_len; s += 8) {
        const float* vrow = (s == start_pos)
            ? vnew
            : cache_v + (((size_t)b * MAX_SEQ + s) * HEAD_NUM + h) * D_K;
        const float4 vf = *reinterpret_cast<const float4*>(&vrow[lane32 * 4]);
        const float p = sc[s];
        accv.x = fmaf(p, vf.x, accv.x);
        accv.y = fmaf(p, vf.y, accv.y);
        accv.z = fmaf(p, vf.z, accv.z);
        accv.w = fmaf(p, vf.w, accv.w);
    }
    *reinterpret_cast<float4*>(&partial[grp][lane32 * 4]) = accv;
    __syncthreads();

    if (tid < D_K) {
        float r = 0.f;
        #pragma unroll
        for (int g = 0; g < 8; ++g) r += partial[g][tid];
        attn_out[b * HIDDEN + h * D_K + tid] = r * inv_sum;
    }
}

// ---------------------------------------------------------------------------
// Kernel 3: out = attn_out @ w_o. Same k-split structure as kernel 1,
// atomics into memset-zeroed d_out. 16 colTiles x 16 kChunks = 256 blocks.
// ---------------------------------------------------------------------------
__global__ __launch_bounds__(256) void oproj_kernel(
    const float* __restrict__ attn_out,
    const float* __restrict__ w_o,
    float* __restrict__ out)
{
    __shared__ float xs[MAX_BS][256];
    const int colTile = blockIdx.x;   // 0..15
    const int kChunk  = blockIdx.y;   // 0..15 (chunks of 256)
    const int tid     = threadIdx.x;

    for (int idx = tid; idx < MAX_BS * 256 / 4; idx += 256) {
        int b = idx >> 6;
        int f = idx & 63;
        *reinterpret_cast<float4*>(&xs[b][f * 4]) =
            *reinterpret_cast<const float4*>(&attn_out[b * HIDDEN + kChunk * 256 + f * 4]);
    }
    __syncthreads();

    const int col = colTile * 256 + tid;
    float acc[MAX_BS];
    #pragma unroll
    for (int b = 0; b < MAX_BS; ++b) acc[b] = 0.f;

    const float* wcol = w_o + (size_t)(kChunk * 256) * HIDDEN + col;
    #pragma unroll 4
    for (int ii = 0; ii < 256; ++ii) {
        float w = wcol[(size_t)ii * HIDDEN];
        #pragma unroll
        for (int b = 0; b < MAX_BS; ++b)
            acc[b] = fmaf(xs[b][ii], w, acc[b]);
    }

    #pragma unroll
    for (int b = 0; b < MAX_BS; ++b)
        atomicAdd(&out[b * HIDDEN + col], acc[b]);
}

extern "C" void kernel_launch(void* const* d_in, const int* in_sizes, int n_in,
                              void* d_out, int out_size, void* d_ws, size_t ws_size,
                              hipStream_t stream) {
    const float* x       = (const float*)d_in[0];
    const float* cache_k = (const float*)d_in[1];
    const float* cache_v = (const float*)d_in[2];
    const float* w_q     = (const float*)d_in[3];
    const float* w_k     = (const float*)d_in[4];
    const float* w_v     = (const float*)d_in[5];
    const float* w_o     = (const float*)d_in[6];
    const int*   start_pos = (const int*)d_in[7];

    float* out      = (float*)d_out;
    float* qkv      = (float*)d_ws;                        // 3*16*4096 floats
    float* attn_out = qkv + 3 * MAX_BS * HIDDEN;           // 16*4096 floats

    // zero accumulation targets every call (graph replays reuse buffers)
    hipMemsetAsync(qkv, 0, (size_t)3 * MAX_BS * HIDDEN * sizeof(float), stream);
    hipMemsetAsync(d_out, 0, (size_t)out_size * sizeof(float), stream);

    qkv_kernel<<<dim3(16, 8, 3), 256, 0, stream>>>(x, w_q, w_k, w_v, qkv);
    attn_kernel<<<dim3(HEAD_NUM, MAX_BS), 256, 0, stream>>>(cache_k, cache_v, qkv,
                                                            start_pos, attn_out);
    oproj_kernel<<<dim3(16, 16), 256, 0, stream>>>(attn_out, w_o, out);
}

// Round 2
// 269.046 us; speedup vs baseline: 1.7307x; 1.7307x over previous
//
#include <hip/hip_runtime.h>

#define HEAD_NUM 32
#define D_K 128
#define HIDDEN 4096
#define MAX_BS 16
#define MAX_SEQ 2048
#define NCHUNK 8        // seq chunks for flash-decoding split
#define CHUNK 256       // MAX_SEQ / NCHUNK

// ---------------------------------------------------------------------------
// Kernel 1: q/k/v = x @ {w_q,w_k,w_v}. k-split x32 for occupancy (1536 blocks).
// ---------------------------------------------------------------------------
__global__ __launch_bounds__(256) void qkv_kernel(
    const float* __restrict__ x,
    const float* __restrict__ w_q,
    const float* __restrict__ w_k,
    const float* __restrict__ w_v,
    float* __restrict__ qkv)     // [3][MAX_BS][HIDDEN], pre-zeroed
{
    __shared__ float xs[MAX_BS][128];
    const int colTile = blockIdx.x;   // 0..15
    const int kChunk  = blockIdx.y;   // 0..31 (chunks of 128 along reduction)
    const int mat     = blockIdx.z;   // 0..2
    const int tid     = threadIdx.x;

    const float* W = (mat == 0) ? w_q : (mat == 1) ? w_k : w_v;
    float* outp = qkv + (size_t)mat * (MAX_BS * HIDDEN);

    for (int idx = tid; idx < MAX_BS * 128 / 4; idx += 256) {
        int b = idx >> 5;        // 32 float4 per row
        int f = idx & 31;
        *reinterpret_cast<float4*>(&xs[b][f * 4]) =
            *reinterpret_cast<const float4*>(&x[b * HIDDEN + kChunk * 128 + f * 4]);
    }
    __syncthreads();

    const int col = colTile * 256 + tid;
    float acc[MAX_BS];
    #pragma unroll
    for (int b = 0; b < MAX_BS; ++b) acc[b] = 0.f;

    const float* wcol = W + (size_t)(kChunk * 128) * HIDDEN + col;
    #pragma unroll 4
    for (int ii = 0; ii < 128; ++ii) {
        float w = wcol[(size_t)ii * HIDDEN];   // coalesced across lanes
        #pragma unroll
        for (int b = 0; b < MAX_BS; ++b)
            acc[b] = fmaf(xs[b][ii], w, acc[b]);
    }

    #pragma unroll
    for (int b = 0; b < MAX_BS; ++b)
        atomicAdd(&outp[b * HIDDEN + col], acc[b]);
}

// ---------------------------------------------------------------------------
// Kernel 2a: partial attention (flash-decoding). One block per (h, b, chunk).
// Produces unnormalized PV partial + (m, l) per chunk.
// ---------------------------------------------------------------------------
__global__ __launch_bounds__(256) void attn_partial_kernel(
    const float* __restrict__ cache_k,
    const float* __restrict__ cache_v,
    const float* __restrict__ qkv,
    const int*   __restrict__ start_pos_p,
    float* __restrict__ part_o,    // [B][H][NCHUNK][D_K]
    float* __restrict__ part_ml)   // [B][H][NCHUNK][2]
{
    const int h   = blockIdx.x;
    const int b   = blockIdx.y;
    const int c   = blockIdx.z;
    const int tid = threadIdx.x;
    const int start_pos = *start_pos_p;
    const int seq_len   = start_pos + 1;
    const int s0        = c * CHUNK;

    __shared__ float sc[CHUNK];          // one score per thread
    __shared__ float red[8];
    __shared__ float partial[8][D_K];

    const float* q    = qkv + b * HIDDEN + h * D_K;
    const float* knew = qkv + 1 * (MAX_BS * HIDDEN) + b * HIDDEN + h * D_K;
    const float* vnew = qkv + 2 * (MAX_BS * HIDDEN) + b * HIDDEN + h * D_K;

    const int lane32 = tid & 31;
    const int grp    = tid >> 5;         // 0..7
    const int wid    = tid >> 6;         // 0..3

    const float4 qf = *reinterpret_cast<const float4*>(&q[lane32 * 4]);
    const float scale = 0.08838834764831845f;   // 1/sqrt(128)

    sc[tid] = -INFINITY;
    __syncthreads();

    // ---- scores for this chunk ------------------------------------------
    for (int r = grp; r < CHUNK; r += 8) {
        const int s = s0 + r;
        if (s >= seq_len) break;
        const float* krow = (s == start_pos)
            ? knew
            : cache_k + (((size_t)b * MAX_SEQ + s) * HEAD_NUM + h) * D_K;
        const float4 kf = *reinterpret_cast<const float4*>(&krow[lane32 * 4]);
        float p = qf.x * kf.x + qf.y * kf.y + qf.z * kf.z + qf.w * kf.w;
        p += __shfl_xor(p, 16);
        p += __shfl_xor(p, 8);
        p += __shfl_xor(p, 4);
        p += __shfl_xor(p, 2);
        p += __shfl_xor(p, 1);
        if (lane32 == 0) sc[r] = p * scale;
    }
    __syncthreads();

    // ---- local softmax stats (thread tid owns sc[tid]) -------------------
    float m = sc[tid];
    #pragma unroll
    for (int off = 32; off; off >>= 1) m = fmaxf(m, __shfl_xor(m, off));
    if ((tid & 63) == 0) red[wid] = m;
    __syncthreads();
    m = fmaxf(fmaxf(red[0], red[1]), fmaxf(red[2], red[3]));

    const float raw = sc[tid];
    const float e = (raw == -INFINITY) ? 0.f : __expf(raw - m);
    sc[tid] = e;
    float sum = e;
    #pragma unroll
    for (int off = 32; off; off >>= 1) sum += __shfl_xor(sum, off);
    if ((tid & 63) == 0) red[4 + wid] = sum;
    __syncthreads();
    sum = red[4] + red[5] + red[6] + red[7];

    // ---- unnormalized PV -------------------------------------------------
    float4 accv = {0.f, 0.f, 0.f, 0.f};
    for (int r = grp; r < CHUNK; r += 8) {
        const int s = s0 + r;
        if (s >= seq_len) break;
        const float* vrow = (s == start_pos)
            ? vnew
            : cache_v + (((size_t)b * MAX_SEQ + s) * HEAD_NUM + h) * D_K;
        const float4 vf = *reinterpret_cast<const float4*>(&vrow[lane32 * 4]);
        const float p = sc[r];
        accv.x = fmaf(p, vf.x, accv.x);
        accv.y = fmaf(p, vf.y, accv.y);
        accv.z = fmaf(p, vf.z, accv.z);
        accv.w = fmaf(p, vf.w, accv.w);
    }
    *reinterpret_cast<float4*>(&partial[grp][lane32 * 4]) = accv;
    __syncthreads();

    const size_t base = (size_t)(b * HEAD_NUM + h) * NCHUNK + c;
    if (tid < D_K) {
        float r = 0.f;
        #pragma unroll
        for (int g = 0; g < 8; ++g) r += partial[g][tid];
        part_o[base * D_K + tid] = r;
    }
    if (tid == 0) {
        part_ml[base * 2 + 0] = m;
        part_ml[base * 2 + 1] = sum;
    }
}

// ---------------------------------------------------------------------------
// Kernel 2b: combine chunk partials -> attn_out.
// ---------------------------------------------------------------------------
__global__ __launch_bounds__(128) void attn_combine_kernel(
    const float* __restrict__ part_o,
    const float* __restrict__ part_ml,
    float* __restrict__ attn_out)
{
    const int h   = blockIdx.x;
    const int b   = blockIdx.y;
    const int tid = threadIdx.x;     // 0..127
    const size_t base = (size_t)(b * HEAD_NUM + h) * NCHUNK;

    float mv[NCHUNK];
    float M = -INFINITY;
    #pragma unroll
    for (int c = 0; c < NCHUNK; ++c) {
        mv[c] = part_ml[(base + c) * 2];
        M = fmaxf(M, mv[c]);
    }
    float acc = 0.f, l = 0.f;
    #pragma unroll
    for (int c = 0; c < NCHUNK; ++c) {
        const float w = __expf(mv[c] - M);   // -inf chunks -> 0
        acc += w * part_o[(base + c) * D_K + tid];
        l   += w * part_ml[(base + c) * 2 + 1];
    }
    attn_out[b * HIDDEN + h * D_K + tid] = acc / l;
}

// ---------------------------------------------------------------------------
// Kernel 3: out = attn_out @ w_o. k-split x32 (512 blocks).
// ---------------------------------------------------------------------------
__global__ __launch_bounds__(256) void oproj_kernel(
    const float* __restrict__ attn_out,
    const float* __restrict__ w_o,
    float* __restrict__ out)
{
    __shared__ float xs[MAX_BS][128];
    const int colTile = blockIdx.x;   // 0..15
    const int kChunk  = blockIdx.y;   // 0..31 (chunks of 128)
    const int tid     = threadIdx.x;

    for (int idx = tid; idx < MAX_BS * 128 / 4; idx += 256) {
        int b = idx >> 5;
        int f = idx & 31;
        *reinterpret_cast<float4*>(&xs[b][f * 4]) =
            *reinterpret_cast<const float4*>(&attn_out[b * HIDDEN + kChunk * 128 + f * 4]);
    }
    __syncthreads();

    const int col = colTile * 256 + tid;
    float acc[MAX_BS];
    #pragma unroll
    for (int b = 0; b < MAX_BS; ++b) acc[b] = 0.f;

    const float* wcol = w_o + (size_t)(kChunk * 128) * HIDDEN + col;
    #pragma unroll 4
    for (int ii = 0; ii < 128; ++ii) {
        float w = wcol[(size_t)ii * HIDDEN];
        #pragma unroll
        for (int b = 0; b < MAX_BS; ++b)
            acc[b] = fmaf(xs[b][ii], w, acc[b]);
    }

    #pragma unroll
    for (int b = 0; b < MAX_BS; ++b)
        atomicAdd(&out[b * HIDDEN + col], acc[b]);
}

extern "C" void kernel_launch(void* const* d_in, const int* in_sizes, int n_in,
                              void* d_out, int out_size, void* d_ws, size_t ws_size,
                              hipStream_t stream) {
    const float* x       = (const float*)d_in[0];
    const float* cache_k = (const float*)d_in[1];
    const float* cache_v = (const float*)d_in[2];
    const float* w_q     = (const float*)d_in[3];
    const float* w_k     = (const float*)d_in[4];
    const float* w_v     = (const float*)d_in[5];
    const float* w_o     = (const float*)d_in[6];
    const int*   start_pos = (const int*)d_in[7];

    float* out      = (float*)d_out;
    float* qkv      = (float*)d_ws;                         // 3*16*4096
    float* attn_out = qkv + 3 * MAX_BS * HIDDEN;            // 16*4096
    float* part_o   = attn_out + MAX_BS * HIDDEN;           // 16*32*8*128
    float* part_ml  = part_o + (size_t)MAX_BS * HEAD_NUM * NCHUNK * D_K; // 16*32*8*2

    hipMemsetAsync(qkv, 0, (size_t)3 * MAX_BS * HIDDEN * sizeof(float), stream);
    hipMemsetAsync(d_out, 0, (size_t)out_size * sizeof(float), stream);

    qkv_kernel<<<dim3(16, 32, 3), 256, 0, stream>>>(x, w_q, w_k, w_v, qkv);
    attn_partial_kernel<<<dim3(HEAD_NUM, MAX_BS, NCHUNK), 256, 0, stream>>>(
        cache_k, cache_v, qkv, start_pos, part_o, part_ml);
    attn_combine_kernel<<<dim3(HEAD_NUM, MAX_BS), 128, 0, stream>>>(
        part_o, part_ml, attn_out);
    oproj_kernel<<<dim3(16, 32), 256, 0, stream>>>(attn_out, w_o, out);
}